// Round 6
// baseline (2203.980 us; speedup 1.0000x reference)
//
#include <hip/hip_runtime.h>
#include <stdint.h>

// Word2MatEncoder: out[b] = prod_{s=0..63} table[sent[b,s]]  (28x28 fp32 chain)
//
// R11 = R10 (fused, proven 139us dispatch, VGPR 160) + DMA/compute overlap.
// R10's stall: ~13k cyc/step exposed gather drain (DMA issued then
// immediately vmcnt(0)-waited; 0.89 waves/SIMD so nothing hides it).
// Changes (schedule only; MATMUL/combine/numerics byte-identical to R10):
//  - lds[2] double buffer with STATIC indices (step pairs unrolled: odd
//    steps buf0, even steps buf1) -- no runtime cur^=1.
//  - steady step waits vmcnt(28): current matrix landed, next matrix's 28
//    loads stay in flight across the matmul (m201 counted-vmcnt pattern).
//    Peeled last step waits vmcnt(0). Mid-loop vmem = ONLY dma loads (28/
//    step), so the count is exact.
//  - word-id pointer table staged to LDS at prologue (16 ids/slot, byte
//    offsets): in-loop next-matrix address is a ds_read (lgkmcnt domain) --
//    no mid-loop global pointer-chase, so the compiler never inserts a
//    pipeline-draining vmcnt(0) for address generation.
//  - asm s_waitcnt with "memory" clobber, NO sched_barrier(0) (R9's poison:
//    region pinning broke the loop-interchange register economy -> 256 VGPR
//    + scratch). Ordered objects here are memory ops, which "memory" orders.
//  - dma masked to 56 lanes -> CHUNK_F=224: buffers 2x24.5KB -> 3 blocks/CU.
//  - single-wave blocks: no __syncthreads in the chain loop (combine keeps
//    R10's barriers; vmcnt=0 there so their drain is harmless).
// fp32 throughout (no fp32 MFMA on CDNA4; bf16 error compounds over 63 muls).

#define D 28
#define EMB 784
#define SEQ 64
#define NITEMS 2048
#define LPI 7            // lanes per slot
#define SPW 8            // slots per wave (2 items x 4 segments)
#define RPL 4            // rows of the running product per lane
#define SEG_LEN 16
#define NCHUNK 28        // DMA chunks per matrix-set (1 row x 8 slots each)
#define CHUNK_F 224      // floats per chunk (56 lanes x 16B, lanes 56-63 off)
#define BUF_F (NCHUNK * CHUNK_F)  // 6272 floats = 25088 B per buffer

typedef __attribute__((address_space(3))) uint32_t lds_u32;
typedef const __attribute__((address_space(1))) uint32_t glb_u32;

// Stage one matrix per slot into an LDS buffer. glane = matrix base + rl*16B;
// chunk t pulls row t of each slot's matrix. Lanes 56-63 masked off (their
// exec-masked issues still count once per instruction for the wave's vmcnt:
// 28 loads per dma_mat, always).
__device__ __forceinline__ void dma_mat(const float* glane, float* lds0,
                                        int lane) {
  if (lane < SPW * LPI) {
#pragma unroll
    for (int t = 0; t < NCHUNK; ++t)
      __builtin_amdgcn_global_load_lds((glb_u32*)(glane + t * D),
                                       (lds_u32*)(lds0 + t * CHUNK_F), 16, 0,
                                       0);
  }
}

// Cc = Aa @ M   (M staged in LDS at Bs with the chunk layout) -- R10 verbatim
// modulo CHUNK_F. Bank check: slot bases stride 28 floats, row stride 224
// (mod 32 == 0): 8 slots x 4 consecutive banks cover all 32 -- conflict-free.
#define MATMUL(Aa, Cc)                                                         \
  do {                                                                         \
    _Pragma("unroll") for (int k = 0; k < D; ++k) {                            \
      _Pragma("unroll") for (int jv = 0; jv < 7; ++jv) {                       \
        float4 m = *(const float4*)(Bs + k * CHUNK_F + 4 * jv);                \
        _Pragma("unroll") for (int r = 0; r < RPL; ++r) {                      \
          float a = Aa[r][k];                                                  \
          if (k == 0) {                                                        \
            Cc[r][4 * jv + 0] = a * m.x;                                       \
            Cc[r][4 * jv + 1] = a * m.y;                                       \
            Cc[r][4 * jv + 2] = a * m.z;                                       \
            Cc[r][4 * jv + 3] = a * m.w;                                       \
          } else {                                                             \
            Cc[r][4 * jv + 0] = fmaf(a, m.x, Cc[r][4 * jv + 0]);               \
            Cc[r][4 * jv + 1] = fmaf(a, m.y, Cc[r][4 * jv + 1]);               \
            Cc[r][4 * jv + 2] = fmaf(a, m.z, Cc[r][4 * jv + 2]);               \
            Cc[r][4 * jv + 3] = fmaf(a, m.w, Cc[r][4 * jv + 3]);               \
          }                                                                    \
        }                                                                      \
      }                                                                        \
    }                                                                          \
  } while (0)

// Pipelined step on buffer BI (static 0/1). At step top: outstanding = mat s
// (oldest 28, targeting buf BI) + mat s+1 (newest 28) -> vmcnt(28) retires
// mat s exactly. After compute + lgkm drain, restage THIS buffer with mat
// s+2 (address from the LDS pointer table).
#define STEP(Aa, Cc, BI)                                                       \
  do {                                                                         \
    asm volatile("s_waitcnt vmcnt(28)" ::: "memory");                          \
    const float* Bs = &lds[BI][0] + slot * (LPI * 4);                          \
    MATMUL(Aa, Cc);                                                            \
    asm volatile("s_waitcnt lgkmcnt(0)" ::: "memory");                         \
    if (s + 2 < SEG_LEN) {                                                     \
      uint32_t offn = ptbl[slot * SEG_LEN + s + 2];                            \
      dma_mat((const float*)((const char*)src + offn) + rl * 4, &lds[BI][0],   \
              lane);                                                           \
    }                                                                          \
    ++s;                                                                       \
  } while (0)

#define STEP_LAST(Aa, Cc, BI)                                                  \
  do {                                                                         \
    asm volatile("s_waitcnt vmcnt(0)" ::: "memory");                           \
    const float* Bs = &lds[BI][0] + slot * (LPI * 4);                          \
    MATMUL(Aa, Cc);                                                            \
  } while (0)

// Fused: chain 16 matrices per slot (pipelined), then combine each item's 4
// segment products in-block. One block = 2 items x 4 segments.
__global__ __launch_bounds__(64, 1) void fused_kernel(
    const float* __restrict__ src, const int* __restrict__ sent,
    float* __restrict__ dst, int ntask) {
  __shared__ __align__(16) float lds[2][BUF_F];
  __shared__ uint32_t ptbl[SPW * SEG_LEN];  // per-slot matrix byte offsets

  const int lane = threadIdx.x;
  int slot = lane / LPI;
  int rl = lane - slot * LPI;
  if (slot >= SPW) {  // lanes 56..63 mirror slot 7 (benign duplicates)
    slot = SPW - 1;
    rl = (lane - 56 < LPI) ? lane - 56 : LPI - 1;
  }
  int task = blockIdx.x * SPW + slot;
  if (task >= ntask) task = ntask - 1;

  const int item = task / 4;
  const int seg = task - item * 4;
  const int* sp = sent + item * SEQ + seg * SEG_LEN;

  // Load all 16 word-ids (64B-aligned) and publish byte offsets to LDS.
  // All lanes of a slot write identical values -- benign.
  const int4 w0 = ((const int4*)sp)[0];
  const int4 w1 = ((const int4*)sp)[1];
  const int4 w2 = ((const int4*)sp)[2];
  const int4 w3 = ((const int4*)sp)[3];
#define PW(i, v) ptbl[slot * SEG_LEN + (i)] = (uint32_t)(v) * (EMB * 4u)
  PW(0, w0.x);  PW(1, w0.y);  PW(2, w0.z);  PW(3, w0.w);
  PW(4, w1.x);  PW(5, w1.y);  PW(6, w1.z);  PW(7, w1.w);
  PW(8, w2.x);  PW(9, w2.y);  PW(10, w2.z); PW(11, w2.w);
  PW(12, w3.x); PW(13, w3.y); PW(14, w3.z); PW(15, w3.w);
#undef PW

  float A0[RPL][D], A1[RPL][D];

  // A0 = this lane's rows (rl*4 .. rl*4+3) of matrix 0 (direct loads).
  {
    const float* m0 =
        (const float*)((const char*)src + (uint32_t)w0.x * (EMB * 4u));
#pragma unroll
    for (int r = 0; r < RPL; ++r) {
      const float* rp = m0 + (rl * RPL + r) * D;
#pragma unroll
      for (int jv = 0; jv < 7; ++jv) {
        float4 v = *(const float4*)(rp + 4 * jv);
        A0[r][4 * jv + 0] = v.x;
        A0[r][4 * jv + 1] = v.y;
        A0[r][4 * jv + 2] = v.z;
        A0[r][4 * jv + 3] = v.w;
      }
    }
  }

  // Stage matrices 1 -> buf0 and 2 -> buf1 (56 loads in flight).
  dma_mat((const float*)((const char*)src + (uint32_t)w0.y * (EMB * 4u)) +
              rl * 4,
          &lds[0][0], lane);
  dma_mat((const float*)((const char*)src + (uint32_t)w0.z * (EMB * 4u)) +
              rl * 4,
          &lds[1][0], lane);

  int s = 1;
#pragma unroll 1
  for (int p = 0; p < (SEG_LEN - 2) / 2; ++p) {
    STEP(A0, A1, 0);  // odd steps consume buf0
    STEP(A1, A0, 1);  // even steps consume buf1
  }
  STEP_LAST(A0, A1, 0);  // step 15 -> segment product in A1

  // ---- fused combine: out[item] = ((P0@P1)@P2)@P3 (R10 verbatim) ----
  __syncthreads();  // chain's last LDS reads drained before overwrite

  // writers: slots 1,2,3 -> cols 0,28,56 ; slots 5,6,7 -> cols 84,112,140.
  // layout matches MATMUL's read: element [k][j] at lds[0][k*CHUNK_F+col+j].
  {
    const int wslot = (slot >= 4) ? slot - 4 : slot;  // 0..3 within item
    if (wslot != 0) {
      const int col = ((slot >= 4) ? 3 : 0) * D + (wslot - 1) * D;
      float* wp = &lds[0][0] + col;
#pragma unroll
      for (int r = 0; r < RPL; ++r) {
        const int k = rl * RPL + r;
#pragma unroll
        for (int jv = 0; jv < 7; ++jv) {
          *(float4*)(wp + k * CHUNK_F + 4 * jv) =
              make_float4(A1[r][4 * jv + 0], A1[r][4 * jv + 1],
                          A1[r][4 * jv + 2], A1[r][4 * jv + 3]);
        }
      }
    }
  }
  __syncthreads();  // partials visible to readers

  // readers: slots 0 and 4 chain through their item's 3 partials.
  const int cbase = (slot >= 4) ? 3 * D : 0;
  {
    const float* Bs = &lds[0][0] + cbase + 0 * D;  // P1
    MATMUL(A1, A0);                                // A0 = P0 @ P1
  }
  {
    const float* Bs = &lds[0][0] + cbase + 1 * D;  // P2
    MATMUL(A0, A1);                                // A1 = (P0@P1) @ P2
  }
  {
    const float* Bs = &lds[0][0] + cbase + 2 * D;  // P3
    MATMUL(A1, A0);                                // A0 = ((P0@P1)@P2) @ P3
  }

  // store: only the reader slots (0 and 4) hold a finished item product.
  if (slot == 0 || slot == 4) {
    float* op = dst + (size_t)item * EMB;
#pragma unroll
    for (int r = 0; r < RPL; ++r) {
      float* rp = op + (rl * RPL + r) * D;
#pragma unroll
      for (int jv = 0; jv < 7; ++jv) {
        *(float4*)(rp + 4 * jv) =
            make_float4(A0[r][4 * jv + 0], A0[r][4 * jv + 1],
                        A0[r][4 * jv + 2], A0[r][4 * jv + 3]);
      }
    }
  }
}

extern "C" void kernel_launch(void* const* d_in, const int* in_sizes, int n_in,
                              void* d_out, int out_size, void* d_ws,
                              size_t ws_size, hipStream_t stream) {
  const float* table = (const float*)d_in[0];
  const int* sent = (const int*)d_in[1];
  float* out = (float*)d_out;

  // single fused dispatch: 8192 segment-tasks, 8 per block -> 1024 blocks
  const int ntask = NITEMS * 4;
  fused_kernel<<<ntask / SPW, 64, 0, stream>>>(table, sent, out, ntask);
}